// Round 6
// baseline (663.924 us; speedup 1.0000x reference)
//
#include <hip/hip_runtime.h>
#include <hip/hip_bf16.h>
#include <math.h>

#define N_NODES 32768
#define E_EDGES 524288
#define NHID    256
#define HEAD_DIM 64
#define SEQ     512
#define EPS_LN  1e-5f
// 1/sqrt(64) * log2(e): folded into Q at the QKV-GEMM epilogue, so fattn scores
// are already in exp2 domain: p = exp2(s)
#define SM_SCALE 0.18033688011112042f

typedef __hip_bfloat16 bf16;
typedef __attribute__((ext_vector_type(8))) short short8;   // 8 bf16 (4 VGPRs)
typedef __attribute__((ext_vector_type(4))) float floatx4;  // MFMA accumulator
static const size_t NH = (size_t)N_NODES * NHID;  // 8,388,608

__device__ __forceinline__ void unpack2(unsigned int u, float& lo, float& hi) {
    union { float f; unsigned int i; } a, b;
    a.i = u << 16; b.i = u & 0xffff0000u;
    lo = a.f; hi = b.f;
}

// XOR-swizzled address into a row-major [R][64] bf16 LDS tile (128 B rows).
// byte = row*128 + col*2, then ^= (row&7)<<4 (guide G4 / T2).
__device__ __forceinline__ void* swzp(void* base, int row, int col) {
    return (char*)base + (((row << 7) + (col << 1)) ^ ((row & 7) << 4));
}

// async global->LDS, 16B per lane. LDS dest is wave-uniform base + lane*16 (m104).
__device__ __forceinline__ void gload16(const bf16* g, void* lds) {
    __builtin_amdgcn_global_load_lds((const __attribute__((address_space(1))) void*)g,
                                     (__attribute__((address_space(3))) void*)lds, 16, 0, 0);
}

// ---------------- staging: fp32 -> bf16 cast (x input) ----------------
__global__ void k_cvtb4(bf16* __restrict__ dst, const float* __restrict__ src) {
    size_t i = (size_t)(blockIdx.x * 256 + threadIdx.x) * 4;
    const float4 v = *(const float4*)(src + i);
    __align__(8) bf16 tmp[4];
    tmp[0] = __float2bfloat16(v.x);
    tmp[1] = __float2bfloat16(v.y);
    tmp[2] = __float2bfloat16(v.z);
    tmp[3] = __float2bfloat16(v.w);
    *(uint2*)(dst + i) = *(uint2*)tmp;
}

// ---------------- fused per-layer weight staging ----------------
// blocks 0..191: iw cvt; 192..255: ow cvt; 256..511: conv_w transpose+cast; 512: BN fold.
__global__ __launch_bounds__(256) void k_stage(const float* __restrict__ cw,
                                               const float* __restrict__ bng,
                                               const float* __restrict__ bnb,
                                               const float* __restrict__ bnm,
                                               const float* __restrict__ bnv,
                                               const float* __restrict__ iw,
                                               const float* __restrict__ ow,
                                               bf16* __restrict__ iwb,
                                               bf16* __restrict__ owb,
                                               bf16* __restrict__ cwT,
                                               float* __restrict__ bns,
                                               float* __restrict__ bnt) {
    const int blk = blockIdx.x;
    const int tid = threadIdx.x;
    if (blk < 256) {
        const float* src = (blk < 192) ? iw : ow;
        bf16* dst = (blk < 192) ? iwb : owb;
        size_t i = (size_t)((blk < 192 ? blk : blk - 192) * 256 + tid) * 4;
        const float4 v = *(const float4*)(src + i);
        __align__(8) bf16 t4[4];
        t4[0] = __float2bfloat16(v.x);
        t4[1] = __float2bfloat16(v.y);
        t4[2] = __float2bfloat16(v.z);
        t4[3] = __float2bfloat16(v.w);
        *(uint2*)(dst + i) = *(uint2*)t4;
    } else if (blk < 512) {
        const int k = blk - 256;
        cwT[(size_t)tid * 256 + k] = __float2bfloat16(cw[(size_t)k * 256 + tid]);
    } else {
        float sv = bng[tid] * rsqrtf(bnv[tid] + EPS_LN);
        bns[tid] = sv;
        bnt[tid] = bnb[tid] - bnm[tid] * sv;
    }
}

// ---------------- CSR build: histogram -> scan -> fill ----------------
__global__ void k_hist(const int* __restrict__ edst, int* __restrict__ counts) {
    int e = blockIdx.x * 256 + threadIdx.x;
    atomicAdd(&counts[edst[e]], 1);
}

__global__ __launch_bounds__(256) void k_scan(const int* __restrict__ counts,
                                              int* __restrict__ offsets,
                                              int* __restrict__ cursor) {
    __shared__ int sums[256];
    const int tid = threadIdx.x;
    const int base = tid * 128;
    int s = 0;
    for (int i = 0; i < 128; ++i) s += counts[base + i];
    sums[tid] = s;
    __syncthreads();
    for (int off = 1; off < 256; off <<= 1) {
        int v = (tid >= off) ? sums[tid - off] : 0;
        __syncthreads();
        sums[tid] += v;
        __syncthreads();
    }
    int run = (tid == 0) ? 0 : sums[tid - 1];
    for (int i = 0; i < 128; ++i) {
        int c = counts[base + i];
        offsets[base + i] = run;
        cursor[base + i] = run;
        run += c;
    }
    if (tid == 255) offsets[32768] = run;
}

__global__ void k_fill(const int* __restrict__ esrc, const int* __restrict__ edst,
                       const float* __restrict__ eattr, int* __restrict__ cursor,
                       int* __restrict__ srcp, float* __restrict__ attrp) {
    int e = blockIdx.x * 256 + threadIdx.x;
    int d = edst[e];
    int slot = atomicAdd(&cursor[d], 1);
    srcp[slot] = esrc[e];
    attrp[slot] = eattr[e];
}

// ---------------- conv gather + fused BN: one wave per dst node; bf16 out ----------------
// Two edges per iteration (half-waves), 16 B/lane loads.
__global__ __launch_bounds__(256) void k_gather(const bf16* __restrict__ t,
                                                const int* __restrict__ offsets,
                                                const int* __restrict__ srcp,
                                                const float* __restrict__ attrp,
                                                const float* __restrict__ bns,
                                                const float* __restrict__ bnt,
                                                bf16* __restrict__ conv) {
    const int node = (blockIdx.x * 256 + threadIdx.x) >> 6;
    const int lane = threadIdx.x & 63;
    const int half = lane >> 5;
    const int l32 = lane & 31;
    const int start = offsets[node];
    const int end = offsets[node + 1];
    float a[8];
#pragma unroll
    for (int i = 0; i < 8; ++i) a[i] = 0.f;
    for (int c0 = start; c0 < end; c0 += 64) {
        const int n = min(64, end - c0);
        int sidx = 0;
        float sa = 0.f;
        if (lane < n) {
            sidx = srcp[c0 + lane];
            sa = attrp[c0 + lane];
        }
        for (int j = 0; j < n; j += 2) {
            const int e = j + half;              // e==n on odd tail: that lane's sa==0
            const int s = __shfl(sidx, e, 64);
            const float aw = __shfl(sa, e, 64);
            const uint4 u = *(const uint4*)(t + (size_t)s * 256 + l32 * 8);
            float v0, v1, v2, v3, v4, v5, v6, v7;
            unpack2(u.x, v0, v1);
            unpack2(u.y, v2, v3);
            unpack2(u.z, v4, v5);
            unpack2(u.w, v6, v7);
            a[0] = fmaf(aw, v0, a[0]);
            a[1] = fmaf(aw, v1, a[1]);
            a[2] = fmaf(aw, v2, a[2]);
            a[3] = fmaf(aw, v3, a[3]);
            a[4] = fmaf(aw, v4, a[4]);
            a[5] = fmaf(aw, v5, a[5]);
            a[6] = fmaf(aw, v6, a[6]);
            a[7] = fmaf(aw, v7, a[7]);
        }
    }
#pragma unroll
    for (int i = 0; i < 8; ++i) a[i] += __shfl_xor(a[i], 32, 64);
    if (half == 0) {
        const int c = l32 * 8;
        const float4 s0 = *(const float4*)(bns + c);
        const float4 s1 = *(const float4*)(bns + c + 4);
        const float4 t0 = *(const float4*)(bnt + c);
        const float4 t1 = *(const float4*)(bnt + c + 4);
        __align__(16) bf16 tmp[8];
        tmp[0] = __float2bfloat16(fmaf(a[0], s0.x, t0.x));
        tmp[1] = __float2bfloat16(fmaf(a[1], s0.y, t0.y));
        tmp[2] = __float2bfloat16(fmaf(a[2], s0.z, t0.z));
        tmp[3] = __float2bfloat16(fmaf(a[3], s0.w, t0.w));
        tmp[4] = __float2bfloat16(fmaf(a[4], s1.x, t1.x));
        tmp[5] = __float2bfloat16(fmaf(a[5], s1.y, t1.y));
        tmp[6] = __float2bfloat16(fmaf(a[6], s1.z, t1.z));
        tmp[7] = __float2bfloat16(fmaf(a[7], s1.w, t1.w));
        *(uint4*)(conv + (size_t)node * 256 + c) = *(uint4*)tmp;
    }
}

// ---------------- MFMA GEMM: C[32768 x N] = A[32768x256] @ B, B staged as WT[n][k] ----
// T3-minimum double-buffer (fattn-R3 pattern): STAGE(next) issued BEFORE compute of
// current K-step, one barrier per step — global latency hides under the 32 MFMA.
// LDS 64 KB -> 2 blocks/CU. global_load_lds (linear dest, inverse-swz source) +
// XOR-swizzled ds_read_b128 (rule #21).
// qkvmode: Q-slice (gc<256) scaled by SM_SCALE; V-slice (gc>=512) written transposed
// to VT[(b*4+head)*64+d][512].
__global__ __launch_bounds__(256) void k_gemm(const bf16* __restrict__ A,
                                              const bf16* __restrict__ WT,
                                              const float* __restrict__ bias,
                                              bf16* __restrict__ C, bf16* __restrict__ VT,
                                              int ldc, int qkvmode) {
    __shared__ __align__(16) short As[2][128 * 64];
    __shared__ __align__(16) short Bs[2][128 * 64];
    const int tid = threadIdx.x;
    const int bm = blockIdx.x * 128;
    const int bn = blockIdx.y * 128;
    const int wid = tid >> 6;
    const int lane = tid & 63;
    const int wr = (wid >> 1) * 64;
    const int wc = (wid & 1) * 64;
    const int quad = lane >> 4;
    const int l16 = lane & 15;

    floatx4 acc[4][4];
#pragma unroll
    for (int mi = 0; mi < 4; ++mi)
#pragma unroll
        for (int ni = 0; ni < 4; ++ni)
            acc[mi][ni] = (floatx4){0.f, 0.f, 0.f, 0.f};

    // stage K-step ks (64 cols) into buffer bf
    auto STAGE = [&](int ks, int bf) {
#pragma unroll
        for (int t = 0; t < 4; ++t) {
            const int p = ((t * 4 + wid) << 10) + (lane << 4);  // linear LDS byte
            const int row = p >> 7;
            const int cb = (p & 127) ^ ((row & 7) << 4);        // inverse-swz source col
            gload16(A + (size_t)(bm + row) * 256 + ks * 64 + (cb >> 1),
                    (char*)&As[bf][0] + ((t * 4 + wid) << 10));
            gload16(WT + (size_t)(bn + row) * 256 + ks * 64 + (cb >> 1),
                    (char*)&Bs[bf][0] + ((t * 4 + wid) << 10));
        }
    };

    STAGE(0, 0);
    __syncthreads();
    for (int t = 0; t < 4; ++t) {
        const int buf = t & 1;
        if (t < 3) STAGE(t + 1, buf ^ 1);  // in flight during this step's MFMA
#pragma unroll
        for (int kk = 0; kk < 2; ++kk) {
            const int kcol = kk * 32 + quad * 8;
            short8 af[4], bfr[4];
#pragma unroll
            for (int mi = 0; mi < 4; ++mi)
                af[mi] = *(const short8*)swzp(&As[buf][0], wr + mi * 16 + l16, kcol);
#pragma unroll
            for (int ni = 0; ni < 4; ++ni)
                bfr[ni] = *(const short8*)swzp(&Bs[buf][0], wc + ni * 16 + l16, kcol);
#pragma unroll
            for (int mi = 0; mi < 4; ++mi)
#pragma unroll
                for (int ni = 0; ni < 4; ++ni)
                    acc[mi][ni] = __builtin_amdgcn_mfma_f32_16x16x32_bf16(af[mi], bfr[ni],
                                                                          acc[mi][ni], 0, 0, 0);
        }
        __syncthreads();  // drains prefetch + guards buf reuse
    }
    const float cs = (qkvmode && bn < 256) ? SM_SCALE : 1.0f;
    const bool vpath = (qkvmode && bn >= 512);
#pragma unroll
    for (int ni = 0; ni < 4; ++ni) {
        const int gc = bn + wc + ni * 16 + l16;
        const float bv = bias ? bias[gc] : 0.f;
#pragma unroll
        for (int mi = 0; mi < 4; ++mi) {
            const int gr = bm + wr + mi * 16 + quad * 4;
            if (vpath) {
                // transposed V write: rows gr..gr+3 are consecutive s within graph
                const int head = (gc - 512) >> 6;
                const int d = (gc - 512) & 63;
                const int bg = gr >> 9;        // graph (128-row tiles never cross)
                const int sl = gr & 511;
                __align__(8) bf16 t4[4];
#pragma unroll
                for (int r = 0; r < 4; ++r) t4[r] = __float2bfloat16(acc[mi][ni][r] + bv);
                *(uint2*)(VT + (((size_t)((bg * 4 + head) * 64 + d)) << 9) + sl) = *(uint2*)t4;
            } else {
#pragma unroll
                for (int r = 0; r < 4; ++r)
                    C[(size_t)(gr + r) * ldc + gc] = __float2bfloat16((acc[mi][ni][r] + bv) * cs);
            }
        }
    }
}

// ---------------- MFMA flash attention — barrier-free streaming ----------------
// block = (graph, head, 64-row q-tile); 4 fully-independent waves (NO __syncthreads).
// K and V^T tiles are L2-resident (8 KB each per (b,head,kt); XCD swizzle keeps all
// consumers on one XCD) and their MFMA B-fragments are 16 B/lane contiguous in
// global memory, with the two k-halves covering full 128-B lines -> K/V are read
// DIRECTLY from global, no LDS staging, no vmcnt-drain barriers. Only the per-wave
// Ps round-trip stays in LDS (lgkmcnt-ordered within the wave). 4x read redundancy
// across waves ~21 TB/s L2 aggregate, under the 34.5 ceiling. LDS 40960->8192 B.
// No-max softmax (Q pre-scaled, exp2 domain); l-sum via MFMA ones-column.
// setprio removed (R5: -10% — waves here were barrier-lockstepped; m190 regime).
__global__ __launch_bounds__(256) void k_fattn(const bf16* __restrict__ qkv,
                                               const bf16* __restrict__ vtb,
                                               bf16* __restrict__ ctx) {
    const int bid = ((blockIdx.x & 7) << 8) | (blockIdx.x >> 3);
    const int qt = bid & 7;
    const int head = (bid >> 3) & 3;
    const int b = bid >> 5;
    const int tid = threadIdx.x;
    const int wave = tid >> 6;
    const int lane = tid & 63;
    const int quad = lane >> 4;
    const int l16 = lane & 15;
    const int qrow0 = b * SEQ + qt * 64 + wave * 16;

    __shared__ __align__(16) short Ps[4][16 * 64];   // per-wave [q][key] swizzled

    // per-lane row base pointers (row = l16 within each 16-row group)
    const bf16* krow = qkv + (size_t)(b * SEQ + l16) * 768 + 256 + head * HEAD_DIM + quad * 8;
    const bf16* vrow = vtb + (size_t)((b * 4 + head) * 64 + l16) * 512 + quad * 8;

    short8 af_q[2];
    {
        const bf16* qp = qkv + (size_t)(qrow0 + l16) * 768 + head * HEAD_DIM + quad * 8;
        af_q[0] = *(const short8*)(qp);
        af_q[1] = *(const short8*)(qp + 32);
    }
    short8 ones;
#pragma unroll
    for (int j = 0; j < 8; ++j) ones[j] = (short)0x3F80;  // bf16(1.0)

    floatx4 acc[5];  // [0..3]: PV d-blocks; [4]: row-sum l
#pragma unroll
    for (int nt = 0; nt < 5; ++nt) acc[nt] = (floatx4){0.f, 0.f, 0.f, 0.f};

    bf16* psb = (bf16*)&Ps[wave][0];

    for (int kt = 0; kt < 8; ++kt) {
        // QK^T: B-fragment (K rows f*16+l16, 16 B @ quad*8) streamed from global
        floatx4 sf[4];
#pragma unroll
        for (int f = 0; f < 4; ++f) {
            const bf16* kp = krow + (size_t)(kt * 64 + f * 16) * 768;
            const short8 bk0 = *(const short8*)(kp);
            const short8 bk1 = *(const short8*)(kp + 32);
            sf[f] = __builtin_amdgcn_mfma_f32_16x16x32_bf16(af_q[0], bk0,
                                                            (floatx4){0.f, 0.f, 0.f, 0.f}, 0, 0, 0);
            sf[f] = __builtin_amdgcn_mfma_f32_16x16x32_bf16(af_q[1], bk1, sf[f], 0, 0, 0);
        }

#pragma unroll
        for (int r = 0; r < 4; ++r) {
            const float p0 = exp2f(fminf(sf[0][r], 80.f));
            const float p1 = exp2f(fminf(sf[1][r], 80.f));
            const float p2 = exp2f(fminf(sf[2][r], 80.f));
            const float p3 = exp2f(fminf(sf[3][r], 80.f));
            const int qr = quad * 4 + r;
            *(bf16*)swzp(psb, qr, l16)      = __float2bfloat16(p0);
            *(bf16*)swzp(psb, qr, 16 + l16) = __float2bfloat16(p1);
            *(bf16*)swzp(psb, qr, 32 + l16) = __float2bfloat16(p2);
            *(bf16*)swzp(psb, qr, 48 + l16) = __float2bfloat16(p3);
        }

        // PV: A = P from per-wave LDS; B = V^T rows nt*16+l16 streamed from global
#pragma unroll
        for (int c2 = 0; c2 < 2; ++c2) {
            const short8 ap = *(const short8*)swzp(psb, l16, c2 * 32 + quad * 8);
#pragma unroll
            for (int nt = 0; nt < 4; ++nt) {
                const short8 bv =
                    *(const short8*)(vrow + (size_t)(nt * 16) * 512 + kt * 64 + c2 * 32);
                acc[nt] = __builtin_amdgcn_mfma_f32_16x16x32_bf16(ap, bv, acc[nt], 0, 0, 0);
            }
            acc[4] = __builtin_amdgcn_mfma_f32_16x16x32_bf16(ap, ones, acc[4], 0, 0, 0);
        }
    }

#pragma unroll
    for (int r = 0; r < 4; ++r) {
        const float inv = 1.f / acc[4][r];  // every column of acc[4] = row-sum l
        bf16* op = ctx + (size_t)(qrow0 + quad * 4 + r) * 256 + head * HEAD_DIM + l16;
        op[0]  = __float2bfloat16(acc[0][r] * inv);
        op[16] = __float2bfloat16(acc[1][r] * inv);
        op[32] = __float2bfloat16(acc[2][r] * inv);
        op[48] = __float2bfloat16(acc[3][r] * inv);
    }
}

// ---------------- residual + LayerNorm + ReLU (layer 0); one wave per node ----------------
__global__ void k_ln(const bf16* __restrict__ conv, const bf16* __restrict__ proj,
                     const float* __restrict__ lg, const float* __restrict__ lb,
                     bf16* __restrict__ h) {
    int gt = blockIdx.x * blockDim.x + threadIdx.x;
    int node = gt >> 6;
    int lane = gt & 63;
    size_t base = (size_t)node * 256 + lane * 4;
    uint2 ua = *(const uint2*)(conv + base);
    uint2 up = *(const uint2*)(proj + base);
    float a0, a1, a2, a3, p0, p1, p2, p3;
    unpack2(ua.x, a0, a1);
    unpack2(ua.y, a2, a3);
    unpack2(up.x, p0, p1);
    unpack2(up.y, p2, p3);
    float y0 = a0 + p0, y1 = a1 + p1, y2 = a2 + p2, y3 = a3 + p3;
    float sum = y0 + y1 + y2 + y3;
#pragma unroll
    for (int off = 32; off > 0; off >>= 1) sum += __shfl_xor(sum, off, 64);
    float mu = sum * (1.0f / 256.0f);
    float d0 = y0 - mu, d1 = y1 - mu, d2 = y2 - mu, d3 = y3 - mu;
    float vs = d0 * d0 + d1 * d1 + d2 * d2 + d3 * d3;
#pragma unroll
    for (int off = 32; off > 0; off >>= 1) vs += __shfl_xor(vs, off, 64);
    float r = rsqrtf(vs * (1.0f / 256.0f) + EPS_LN);
    int c = lane * 4;
    float o0 = fmaxf(fmaf(d0 * r, lg[c + 0], lb[c + 0]), 0.f);
    float o1 = fmaxf(fmaf(d1 * r, lg[c + 1], lb[c + 1]), 0.f);
    float o2 = fmaxf(fmaf(d2 * r, lg[c + 2], lb[c + 2]), 0.f);
    float o3 = fmaxf(fmaf(d3 * r, lg[c + 3], lb[c + 3]), 0.f);
    __align__(8) bf16 tmp[4];
    tmp[0] = __float2bfloat16(o0);
    tmp[1] = __float2bfloat16(o1);
    tmp[2] = __float2bfloat16(o2);
    tmp[3] = __float2bfloat16(o3);
    *(uint2*)(h + base) = *(uint2*)tmp;
}

// ---------------- final layer: residual + LayerNorm + fp32 out + scores fused ----------
__global__ void k_lnout(const bf16* __restrict__ conv, const bf16* __restrict__ proj,
                        const float* __restrict__ lg, const float* __restrict__ lb,
                        const float* __restrict__ sw, const float* __restrict__ sb,
                        float* __restrict__ out) {
    int gt = blockIdx.x * blockDim.x + threadIdx.x;
    int node = gt >> 6;
    int lane = gt & 63;
    size_t base = (size_t)node * 256 + lane * 4;
    uint2 ua = *(const uint2*)(conv + base);
    uint2 up = *(const uint2*)(proj + base);
    float a0, a1, a2, a3, p0, p1, p2, p3;
    unpack2(ua.x, a0, a1);
    unpack2(ua.y, a2, a3);
    unpack2(up.x, p0, p1);
    unpack2(up.y, p2, p3);
    float y0 = a0 + p0, y1 = a1 + p1, y2 = a2 + p2, y3 = a3 + p3;
    float sum = y0 + y1 + y2 + y3;
#pragma unroll
    for (int off = 32; off > 0; off >>= 1) sum += __shfl_xor(sum, off, 64);
    float mu = sum * (1.0f / 256.0f);
    float d0 = y0 - mu, d1 = y1 - mu, d2 = y2 - mu, d3 = y3 - mu;
    float vs = d0 * d0 + d1 * d1 + d2 * d2 + d3 * d3;
#pragma unroll
    for (int off = 32; off > 0; off >>= 1) vs += __shfl_xor(vs, off, 64);
    float r = rsqrtf(vs * (1.0f / 256.0f) + EPS_LN);
    int c = lane * 4;
    float o0 = fmaf(d0 * r, lg[c + 0], lb[c + 0]);
    float o1 = fmaf(d1 * r, lg[c + 1], lb[c + 1]);
    float o2 = fmaf(d2 * r, lg[c + 2], lb[c + 2]);
    float o3 = fmaf(d3 * r, lg[c + 3], lb[c + 3]);
    *(float4*)(out + base) = make_float4(o0, o1, o2, o3);
    float part = o0 * sw[c + 0] + o1 * sw[c + 1] + o2 * sw[c + 2] + o3 * sw[c + 3];
#pragma unroll
    for (int off = 32; off > 0; off >>= 1) part += __shfl_xor(part, off, 64);
    if (lane == 0)
        out[(size_t)N_NODES * 256 + node] = part + sb[0];
}

extern "C" void kernel_launch(void* const* d_in, const int* in_sizes, int n_in,
                              void* d_out, int out_size, void* d_ws, size_t ws_size,
                              hipStream_t stream) {
    if (ws_size < (size_t)100663296) return;  // 96 MiB budget (6 * 16 MiB)

    const float* x     = (const float*)d_in[0];
    const int*   esrc  = (const int*)d_in[1];
    const int*   edst  = (const int*)d_in[2];
    const float* eattr = (const float*)d_in[3];

    // ws layout: convb(16M) | qkvb(48M, [node][768]) | tb(16M) | vtb(16M) = 96 MiB
    bf16* convb = (bf16*)d_ws;
    bf16* qkvb  = convb + NH;
    bf16* tb    = qkvb + 3 * NH;
    bf16* vtb   = tb + NH;
    // overlays (raw byte-range reuse; all dead at time of overwrite):
    bf16* xb  = qkvb;       // x-cast, dead after layer-0 conv GEMM
    bf16* hb  = qkvb + NH;  // h, dead after next layer's conv GEMM
    bf16* pjb = qkvb;       // proj out, written after fattn consumed qkv

    char* scr = (char*)d_out;
    const size_t LBYTES = 393216 + 131072 + 131072 + 2048;
    int*   counts  = (int*)(scr + 2 * LBYTES);
    int*   offsets = counts + 32768;
    int*   cursor  = offsets + 32769;
    int*   srcp    = cursor + 32768;
    float* attrp   = (float*)(srcp + E_EDGES);

    (void)hipMemsetAsync(counts, 0, 32768 * sizeof(int), stream);
    k_hist<<<E_EDGES / 256, 256, 0, stream>>>(edst, counts);
    k_scan<<<1, 256, 0, stream>>>(counts, offsets, cursor);
    k_fill<<<E_EDGES / 256, 256, 0, stream>>>(esrc, edst, eattr, cursor, srcp, attrp);

    for (int L = 0; L < 2; ++L) {
        int bi = 5 + L * 11;
        char* base = scr + (size_t)L * LBYTES;
        bf16*  iwb = (bf16*)base;
        bf16*  owb = iwb + 196608;
        bf16*  cwT = owb + 65536;
        float* bns = (float*)(cwT + 65536);
        float* bnt = bns + 256;
        k_stage<<<513, 256, 0, stream>>>((const float*)d_in[bi + 0], (const float*)d_in[bi + 1],
                                         (const float*)d_in[bi + 2], (const float*)d_in[bi + 3],
                                         (const float*)d_in[bi + 4], (const float*)d_in[bi + 5],
                                         (const float*)d_in[bi + 7], iwb, owb, cwT, bns, bnt);
    }

    k_cvtb4<<<8192, 256, 0, stream>>>(xb, x);

    for (int L = 0; L < 2; ++L) {
        int bi = 5 + L * 11;
        char* base = scr + (size_t)L * LBYTES;
        bf16*  iwb = (bf16*)base;
        bf16*  owb = iwb + 196608;
        bf16*  cwT = owb + 65536;
        float* bns = (float*)(cwT + 65536);
        float* bnt = bns + 256;
        const float* ib = (const float*)d_in[bi + 6];
        const float* ob = (const float*)d_in[bi + 8];

        k_gemm<<<dim3(256, 2), 256, 0, stream>>>(L == 0 ? xb : hb, cwT, nullptr, tb, nullptr,
                                                 256, 0);
        k_gather<<<8192, 256, 0, stream>>>(tb, offsets, srcp, attrp, bns, bnt, convb);
        // fused QKV projection: Q pre-scaled, K to qkvb, V written transposed to vtb
        k_gemm<<<dim3(256, 6), 256, 0, stream>>>(convb, iwb, ib, qkvb, vtb, 768, 1);
        k_fattn<<<2048, 256, 0, stream>>>(qkvb, vtb, tb);
        k_gemm<<<dim3(256, 2), 256, 0, stream>>>(tb, owb, ob, pjb, nullptr, 256, 0);
        if (L == 0) {
            k_ln<<<8192, 256, 0, stream>>>(convb, pjb, (const float*)d_in[bi + 9],
                                           (const float*)d_in[bi + 10], hb);
        } else {
            k_lnout<<<8192, 256, 0, stream>>>(convb, pjb, (const float*)d_in[bi + 9],
                                              (const float*)d_in[bi + 10],
                                              (const float*)d_in[27], (const float*)d_in[28],
                                              (float*)d_out);
        }
    }
}

// Round 7
// 507.510 us; speedup vs baseline: 1.3082x; 1.3082x over previous
//
#include <hip/hip_runtime.h>
#include <hip/hip_bf16.h>
#include <math.h>

#define N_NODES 32768
#define E_EDGES 524288
#define NHID    256
#define HEAD_DIM 64
#define SEQ     512
#define EPS_LN  1e-5f
// 1/sqrt(64) * log2(e): folded into Q at the QKV-GEMM epilogue, so fattn scores
// are already in exp2 domain: p = exp2(s)
#define SM_SCALE 0.18033688011112042f

typedef __hip_bfloat16 bf16;
typedef __attribute__((ext_vector_type(8))) short short8;   // 8 bf16 (4 VGPRs)
typedef __attribute__((ext_vector_type(4))) float floatx4;  // MFMA accumulator
static const size_t NH = (size_t)N_NODES * NHID;  // 8,388,608

__device__ __forceinline__ void unpack2(unsigned int u, float& lo, float& hi) {
    union { float f; unsigned int i; } a, b;
    a.i = u << 16; b.i = u & 0xffff0000u;
    lo = a.f; hi = b.f;
}

// XOR-swizzled address into a row-major [R][64] bf16 LDS tile (128 B rows).
// byte = row*128 + col*2, then ^= (row&7)<<4 (guide G4 / T2).
__device__ __forceinline__ void* swzp(void* base, int row, int col) {
    return (char*)base + (((row << 7) + (col << 1)) ^ ((row & 7) << 4));
}

// async global->LDS, 16B per lane. LDS dest is wave-uniform base + lane*16 (m104).
__device__ __forceinline__ void gload16(const bf16* g, void* lds) {
    __builtin_amdgcn_global_load_lds((const __attribute__((address_space(1))) void*)g,
                                     (__attribute__((address_space(3))) void*)lds, 16, 0, 0);
}

// ---------------- staging: fp32 -> bf16 cast (x input) ----------------
__global__ void k_cvtb4(bf16* __restrict__ dst, const float* __restrict__ src) {
    size_t i = (size_t)(blockIdx.x * 256 + threadIdx.x) * 4;
    const float4 v = *(const float4*)(src + i);
    __align__(8) bf16 tmp[4];
    tmp[0] = __float2bfloat16(v.x);
    tmp[1] = __float2bfloat16(v.y);
    tmp[2] = __float2bfloat16(v.z);
    tmp[3] = __float2bfloat16(v.w);
    *(uint2*)(dst + i) = *(uint2*)tmp;
}

// ---------------- fused per-layer weight staging ----------------
// blocks 0..191: iw cvt; 192..255: ow cvt; 256..511: conv_w transpose+cast; 512: BN fold.
__global__ __launch_bounds__(256) void k_stage(const float* __restrict__ cw,
                                               const float* __restrict__ bng,
                                               const float* __restrict__ bnb,
                                               const float* __restrict__ bnm,
                                               const float* __restrict__ bnv,
                                               const float* __restrict__ iw,
                                               const float* __restrict__ ow,
                                               bf16* __restrict__ iwb,
                                               bf16* __restrict__ owb,
                                               bf16* __restrict__ cwT,
                                               float* __restrict__ bns,
                                               float* __restrict__ bnt) {
    const int blk = blockIdx.x;
    const int tid = threadIdx.x;
    if (blk < 256) {
        const float* src = (blk < 192) ? iw : ow;
        bf16* dst = (blk < 192) ? iwb : owb;
        size_t i = (size_t)((blk < 192 ? blk : blk - 192) * 256 + tid) * 4;
        const float4 v = *(const float4*)(src + i);
        __align__(8) bf16 t4[4];
        t4[0] = __float2bfloat16(v.x);
        t4[1] = __float2bfloat16(v.y);
        t4[2] = __float2bfloat16(v.z);
        t4[3] = __float2bfloat16(v.w);
        *(uint2*)(dst + i) = *(uint2*)t4;
    } else if (blk < 512) {
        const int k = blk - 256;
        cwT[(size_t)tid * 256 + k] = __float2bfloat16(cw[(size_t)k * 256 + tid]);
    } else {
        float sv = bng[tid] * rsqrtf(bnv[tid] + EPS_LN);
        bns[tid] = sv;
        bnt[tid] = bnb[tid] - bnm[tid] * sv;
    }
}

// ---------------- CSR build: histogram -> scan -> fill ----------------
__global__ void k_hist(const int* __restrict__ edst, int* __restrict__ counts) {
    int e = blockIdx.x * 256 + threadIdx.x;
    atomicAdd(&counts[edst[e]], 1);
}

__global__ __launch_bounds__(256) void k_scan(const int* __restrict__ counts,
                                              int* __restrict__ offsets,
                                              int* __restrict__ cursor) {
    __shared__ int sums[256];
    const int tid = threadIdx.x;
    const int base = tid * 128;
    int s = 0;
    for (int i = 0; i < 128; ++i) s += counts[base + i];
    sums[tid] = s;
    __syncthreads();
    for (int off = 1; off < 256; off <<= 1) {
        int v = (tid >= off) ? sums[tid - off] : 0;
        __syncthreads();
        sums[tid] += v;
        __syncthreads();
    }
    int run = (tid == 0) ? 0 : sums[tid - 1];
    for (int i = 0; i < 128; ++i) {
        int c = counts[base + i];
        offsets[base + i] = run;
        cursor[base + i] = run;
        run += c;
    }
    if (tid == 255) offsets[32768] = run;
}

__global__ void k_fill(const int* __restrict__ esrc, const int* __restrict__ edst,
                       const float* __restrict__ eattr, int* __restrict__ cursor,
                       int* __restrict__ srcp, float* __restrict__ attrp) {
    int e = blockIdx.x * 256 + threadIdx.x;
    int d = edst[e];
    int slot = atomicAdd(&cursor[d], 1);
    srcp[slot] = esrc[e];
    attrp[slot] = eattr[e];
}

// ---------------- conv gather + fused BN: one wave per dst node; bf16 out ----------------
// Two edges per iteration (half-waves), 16 B/lane loads.
__global__ __launch_bounds__(256) void k_gather(const bf16* __restrict__ t,
                                                const int* __restrict__ offsets,
                                                const int* __restrict__ srcp,
                                                const float* __restrict__ attrp,
                                                const float* __restrict__ bns,
                                                const float* __restrict__ bnt,
                                                bf16* __restrict__ conv) {
    const int node = (blockIdx.x * 256 + threadIdx.x) >> 6;
    const int lane = threadIdx.x & 63;
    const int half = lane >> 5;
    const int l32 = lane & 31;
    const int start = offsets[node];
    const int end = offsets[node + 1];
    float a[8];
#pragma unroll
    for (int i = 0; i < 8; ++i) a[i] = 0.f;
    for (int c0 = start; c0 < end; c0 += 64) {
        const int n = min(64, end - c0);
        int sidx = 0;
        float sa = 0.f;
        if (lane < n) {
            sidx = srcp[c0 + lane];
            sa = attrp[c0 + lane];
        }
        for (int j = 0; j < n; j += 2) {
            const int e = j + half;              // e==n on odd tail: that lane's sa==0
            const int s = __shfl(sidx, e, 64);
            const float aw = __shfl(sa, e, 64);
            const uint4 u = *(const uint4*)(t + (size_t)s * 256 + l32 * 8);
            float v0, v1, v2, v3, v4, v5, v6, v7;
            unpack2(u.x, v0, v1);
            unpack2(u.y, v2, v3);
            unpack2(u.z, v4, v5);
            unpack2(u.w, v6, v7);
            a[0] = fmaf(aw, v0, a[0]);
            a[1] = fmaf(aw, v1, a[1]);
            a[2] = fmaf(aw, v2, a[2]);
            a[3] = fmaf(aw, v3, a[3]);
            a[4] = fmaf(aw, v4, a[4]);
            a[5] = fmaf(aw, v5, a[5]);
            a[6] = fmaf(aw, v6, a[6]);
            a[7] = fmaf(aw, v7, a[7]);
        }
    }
#pragma unroll
    for (int i = 0; i < 8; ++i) a[i] += __shfl_xor(a[i], 32, 64);
    if (half == 0) {
        const int c = l32 * 8;
        const float4 s0 = *(const float4*)(bns + c);
        const float4 s1 = *(const float4*)(bns + c + 4);
        const float4 t0 = *(const float4*)(bnt + c);
        const float4 t1 = *(const float4*)(bnt + c + 4);
        __align__(16) bf16 tmp[8];
        tmp[0] = __float2bfloat16(fmaf(a[0], s0.x, t0.x));
        tmp[1] = __float2bfloat16(fmaf(a[1], s0.y, t0.y));
        tmp[2] = __float2bfloat16(fmaf(a[2], s0.z, t0.z));
        tmp[3] = __float2bfloat16(fmaf(a[3], s0.w, t0.w));
        tmp[4] = __float2bfloat16(fmaf(a[4], s1.x, t1.x));
        tmp[5] = __float2bfloat16(fmaf(a[5], s1.y, t1.y));
        tmp[6] = __float2bfloat16(fmaf(a[6], s1.z, t1.z));
        tmp[7] = __float2bfloat16(fmaf(a[7], s1.w, t1.w));
        *(uint4*)(conv + (size_t)node * 256 + c) = *(uint4*)tmp;
    }
}

// ---------------- MFMA GEMM: C[32768 x N] = A[32768x256] @ B, B staged as WT[n][k] ----
// T3-minimum double-buffer: STAGE(next) issued BEFORE compute of current K-step,
// one barrier per step (R6: isolated ~-5us vs single-buffer).
// qkvmode: Q-slice (gc<256) scaled by SM_SCALE; V-slice (gc>=512) written transposed
// to VT[(b*4+head)*64+d][512].
__global__ __launch_bounds__(256) void k_gemm(const bf16* __restrict__ A,
                                              const bf16* __restrict__ WT,
                                              const float* __restrict__ bias,
                                              bf16* __restrict__ C, bf16* __restrict__ VT,
                                              int ldc, int qkvmode) {
    __shared__ __align__(16) short As[2][128 * 64];
    __shared__ __align__(16) short Bs[2][128 * 64];
    const int tid = threadIdx.x;
    const int bm = blockIdx.x * 128;
    const int bn = blockIdx.y * 128;
    const int wid = tid >> 6;
    const int lane = tid & 63;
    const int wr = (wid >> 1) * 64;
    const int wc = (wid & 1) * 64;
    const int quad = lane >> 4;
    const int l16 = lane & 15;

    floatx4 acc[4][4];
#pragma unroll
    for (int mi = 0; mi < 4; ++mi)
#pragma unroll
        for (int ni = 0; ni < 4; ++ni)
            acc[mi][ni] = (floatx4){0.f, 0.f, 0.f, 0.f};

    // stage K-step ks (64 cols) into buffer bf
    auto STAGE = [&](int ks, int bf) {
#pragma unroll
        for (int t = 0; t < 4; ++t) {
            const int p = ((t * 4 + wid) << 10) + (lane << 4);  // linear LDS byte
            const int row = p >> 7;
            const int cb = (p & 127) ^ ((row & 7) << 4);        // inverse-swz source col
            gload16(A + (size_t)(bm + row) * 256 + ks * 64 + (cb >> 1),
                    (char*)&As[bf][0] + ((t * 4 + wid) << 10));
            gload16(WT + (size_t)(bn + row) * 256 + ks * 64 + (cb >> 1),
                    (char*)&Bs[bf][0] + ((t * 4 + wid) << 10));
        }
    };

    STAGE(0, 0);
    __syncthreads();
    for (int t = 0; t < 4; ++t) {
        const int buf = t & 1;
        if (t < 3) STAGE(t + 1, buf ^ 1);  // in flight during this step's MFMA
#pragma unroll
        for (int kk = 0; kk < 2; ++kk) {
            const int kcol = kk * 32 + quad * 8;
            short8 af[4], bfr[4];
#pragma unroll
            for (int mi = 0; mi < 4; ++mi)
                af[mi] = *(const short8*)swzp(&As[buf][0], wr + mi * 16 + l16, kcol);
#pragma unroll
            for (int ni = 0; ni < 4; ++ni)
                bfr[ni] = *(const short8*)swzp(&Bs[buf][0], wc + ni * 16 + l16, kcol);
#pragma unroll
            for (int mi = 0; mi < 4; ++mi)
#pragma unroll
                for (int ni = 0; ni < 4; ++ni)
                    acc[mi][ni] = __builtin_amdgcn_mfma_f32_16x16x32_bf16(af[mi], bfr[ni],
                                                                          acc[mi][ni], 0, 0, 0);
        }
        __syncthreads();  // drains prefetch + guards buf reuse
    }
    const float cs = (qkvmode && bn < 256) ? SM_SCALE : 1.0f;
    const bool vpath = (qkvmode && bn >= 512);
#pragma unroll
    for (int ni = 0; ni < 4; ++ni) {
        const int gc = bn + wc + ni * 16 + l16;
        const float bv = bias ? bias[gc] : 0.f;
#pragma unroll
        for (int mi = 0; mi < 4; ++mi) {
            const int gr = bm + wr + mi * 16 + quad * 4;
            if (vpath) {
                // transposed V write: rows gr..gr+3 are consecutive s within graph
                const int head = (gc - 512) >> 6;
                const int d = (gc - 512) & 63;
                const int bg = gr >> 9;        // graph (128-row tiles never cross)
                const int sl = gr & 511;
                __align__(8) bf16 t4[4];
#pragma unroll
                for (int r = 0; r < 4; ++r) t4[r] = __float2bfloat16(acc[mi][ni][r] + bv);
                *(uint2*)(VT + (((size_t)((bg * 4 + head) * 64 + d)) << 9) + sl) = *(uint2*)t4;
            } else {
#pragma unroll
                for (int r = 0; r < 4; ++r)
                    C[(size_t)(gr + r) * ldc + gc] = __float2bfloat16((acc[mi][ni][r] + bv) * cs);
            }
        }
    }
}

// ---------------- MFMA flash attention (R4 structure — best measured: 46.8 us) ----------
// block = (graph, head, 64-row q-tile); 4 waves x 16 q-rows. XCD-chunked bid swizzle.
// LDS double-buffered K/V staged via global_load_lds; loads for tile kt+1 in flight
// during tile kt's compute (LDS staging amortizes L2 latency — R6's direct-stream
// variant was latency-bound at 125 us). No-max softmax (Q pre-scaled, exp2 domain,
// fmin clamp). l-sum via MFMA ones-column. NO setprio (R5: isolated -5us/dispatch,
// m190 lockstep regime).
__global__ __launch_bounds__(256) void k_fattn(const bf16* __restrict__ qkv,
                                               const bf16* __restrict__ vtb,
                                               bf16* __restrict__ ctx) {
    const int bid = ((blockIdx.x & 7) << 8) | (blockIdx.x >> 3);
    const int qt = bid & 7;
    const int head = (bid >> 3) & 3;
    const int b = bid >> 5;
    const int tid = threadIdx.x;
    const int wave = tid >> 6;
    const int lane = tid & 63;
    const int quad = lane >> 4;
    const int l16 = lane & 15;
    const int qrow0 = b * SEQ + qt * 64 + wave * 16;

    __shared__ __align__(16) short Ks[2][64 * 64];   // [key][d] swizzled, dbuf
    __shared__ __align__(16) short Vt[2][64 * 64];   // [d][key] swizzled, dbuf
    __shared__ __align__(16) short Ps[4][16 * 64];   // per-wave [q][key] swizzled

    const bf16* kbase = qkv + (size_t)(b * SEQ) * 768 + 256 + head * HEAD_DIM;
    const bf16* vbase = vtb + (size_t)((b * 4 + head) * 64) * 512;
    const int pbase = (wave << 10) + (lane << 4);

    short8 af_q[2];
    {
        const bf16* qp = qkv + (size_t)(qrow0 + l16) * 768 + head * HEAD_DIM + quad * 8;
        af_q[0] = *(const short8*)(qp);
        af_q[1] = *(const short8*)(qp + 32);
    }
    short8 ones;
#pragma unroll
    for (int j = 0; j < 8; ++j) ones[j] = (short)0x3F80;  // bf16(1.0)

    floatx4 acc[5];  // [0..3]: PV d-blocks; [4]: row-sum l
#pragma unroll
    for (int nt = 0; nt < 5; ++nt) acc[nt] = (floatx4){0.f, 0.f, 0.f, 0.f};

    // stage K/V tile kt2 into LDS buffer `bf` (async, no VGPR round-trip)
    auto STAGE = [&](int kt2, int bf) {
#pragma unroll
        for (int i = 0; i < 2; ++i) {
            const int p = (i << 12) + pbase;          // linear LDS byte
            const int row = p >> 7;                   // 0..63
            const int cb = (p & 127) ^ ((row & 7) << 4);  // inverse-swz source col
            gload16(kbase + (size_t)(kt2 * 64 + row) * 768 + (cb >> 1),
                    (char*)Ks[bf] + (i << 12) + (wave << 10));
            gload16(vbase + (size_t)row * 512 + kt2 * 64 + (cb >> 1),
                    (char*)Vt[bf] + (i << 12) + (wave << 10));
        }
    };

    STAGE(0, 0);
    __syncthreads();  // drain tile-0 loads

    for (int kt = 0; kt < 8; ++kt) {
        const int buf = kt & 1;
        if (kt < 7) STAGE(kt + 1, buf ^ 1);  // in flight during this tile's compute

        floatx4 sf[4];
#pragma unroll
        for (int f = 0; f < 4; ++f) {
            const short8 bk0 = *(const short8*)swzp(Ks[buf], f * 16 + l16, quad * 8);
            const short8 bk1 = *(const short8*)swzp(Ks[buf], f * 16 + l16, 32 + quad * 8);
            sf[f] = __builtin_amdgcn_mfma_f32_16x16x32_bf16(af_q[0], bk0,
                                                            (floatx4){0.f, 0.f, 0.f, 0.f}, 0, 0, 0);
            sf[f] = __builtin_amdgcn_mfma_f32_16x16x32_bf16(af_q[1], bk1, sf[f], 0, 0, 0);
        }

        bf16* psb = (bf16*)&Ps[wave][0];
#pragma unroll
        for (int r = 0; r < 4; ++r) {
            const float p0 = exp2f(fminf(sf[0][r], 80.f));
            const float p1 = exp2f(fminf(sf[1][r], 80.f));
            const float p2 = exp2f(fminf(sf[2][r], 80.f));
            const float p3 = exp2f(fminf(sf[3][r], 80.f));
            const int qr = quad * 4 + r;
            *(bf16*)swzp(psb, qr, l16)      = __float2bfloat16(p0);
            *(bf16*)swzp(psb, qr, 16 + l16) = __float2bfloat16(p1);
            *(bf16*)swzp(psb, qr, 32 + l16) = __float2bfloat16(p2);
            *(bf16*)swzp(psb, qr, 48 + l16) = __float2bfloat16(p3);
        }

#pragma unroll
        for (int c2 = 0; c2 < 2; ++c2) {
            const short8 ap = *(const short8*)swzp(psb, l16, c2 * 32 + quad * 8);
#pragma unroll
            for (int nt = 0; nt < 4; ++nt) {
                const short8 bv = *(const short8*)swzp(Vt[buf], nt * 16 + l16, c2 * 32 + quad * 8);
                acc[nt] = __builtin_amdgcn_mfma_f32_16x16x32_bf16(ap, bv, acc[nt], 0, 0, 0);
            }
            acc[4] = __builtin_amdgcn_mfma_f32_16x16x32_bf16(ap, ones, acc[4], 0, 0, 0);
        }
        __syncthreads();  // drains prefetch (tile ready) + guards buf reuse
    }

#pragma unroll
    for (int r = 0; r < 4; ++r) {
        const float inv = 1.f / acc[4][r];  // every column of acc[4] = row-sum l
        bf16* op = ctx + (size_t)(qrow0 + quad * 4 + r) * 256 + head * HEAD_DIM + l16;
        op[0]  = __float2bfloat16(acc[0][r] * inv);
        op[16] = __float2bfloat16(acc[1][r] * inv);
        op[32] = __float2bfloat16(acc[2][r] * inv);
        op[48] = __float2bfloat16(acc[3][r] * inv);
    }
}

// ---------------- residual + LayerNorm + ReLU (layer 0); one wave per node ----------------
__global__ void k_ln(const bf16* __restrict__ conv, const bf16* __restrict__ proj,
                     const float* __restrict__ lg, const float* __restrict__ lb,
                     bf16* __restrict__ h) {
    int gt = blockIdx.x * blockDim.x + threadIdx.x;
    int node = gt >> 6;
    int lane = gt & 63;
    size_t base = (size_t)node * 256 + lane * 4;
    uint2 ua = *(const uint2*)(conv + base);
    uint2 up = *(const uint2*)(proj + base);
    float a0, a1, a2, a3, p0, p1, p2, p3;
    unpack2(ua.x, a0, a1);
    unpack2(ua.y, a2, a3);
    unpack2(up.x, p0, p1);
    unpack2(up.y, p2, p3);
    float y0 = a0 + p0, y1 = a1 + p1, y2 = a2 + p2, y3 = a3 + p3;
    float sum = y0 + y1 + y2 + y3;
#pragma unroll
    for (int off = 32; off > 0; off >>= 1) sum += __shfl_xor(sum, off, 64);
    float mu = sum * (1.0f / 256.0f);
    float d0 = y0 - mu, d1 = y1 - mu, d2 = y2 - mu, d3 = y3 - mu;
    float vs = d0 * d0 + d1 * d1 + d2 * d2 + d3 * d3;
#pragma unroll
    for (int off = 32; off > 0; off >>= 1) vs += __shfl_xor(vs, off, 64);
    float r = rsqrtf(vs * (1.0f / 256.0f) + EPS_LN);
    int c = lane * 4;
    float o0 = fmaxf(fmaf(d0 * r, lg[c + 0], lb[c + 0]), 0.f);
    float o1 = fmaxf(fmaf(d1 * r, lg[c + 1], lb[c + 1]), 0.f);
    float o2 = fmaxf(fmaf(d2 * r, lg[c + 2], lb[c + 2]), 0.f);
    float o3 = fmaxf(fmaf(d3 * r, lg[c + 3], lb[c + 3]), 0.f);
    __align__(8) bf16 tmp[4];
    tmp[0] = __float2bfloat16(o0);
    tmp[1] = __float2bfloat16(o1);
    tmp[2] = __float2bfloat16(o2);
    tmp[3] = __float2bfloat16(o3);
    *(uint2*)(h + base) = *(uint2*)tmp;
}

// ---------------- final layer: residual + LayerNorm + fp32 out + scores fused ----------
__global__ void k_lnout(const bf16* __restrict__ conv, const bf16* __restrict__ proj,
                        const float* __restrict__ lg, const float* __restrict__ lb,
                        const float* __restrict__ sw, const float* __restrict__ sb,
                        float* __restrict__ out) {
    int gt = blockIdx.x * blockDim.x + threadIdx.x;
    int node = gt >> 6;
    int lane = gt & 63;
    size_t base = (size_t)node * 256 + lane * 4;
    uint2 ua = *(const uint2*)(conv + base);
    uint2 up = *(const uint2*)(proj + base);
    float a0, a1, a2, a3, p0, p1, p2, p3;
    unpack2(ua.x, a0, a1);
    unpack2(ua.y, a2, a3);
    unpack2(up.x, p0, p1);
    unpack2(up.y, p2, p3);
    float y0 = a0 + p0, y1 = a1 + p1, y2 = a2 + p2, y3 = a3 + p3;
    float sum = y0 + y1 + y2 + y3;
#pragma unroll
    for (int off = 32; off > 0; off >>= 1) sum += __shfl_xor(sum, off, 64);
    float mu = sum * (1.0f / 256.0f);
    float d0 = y0 - mu, d1 = y1 - mu, d2 = y2 - mu, d3 = y3 - mu;
    float vs = d0 * d0 + d1 * d1 + d2 * d2 + d3 * d3;
#pragma unroll
    for (int off = 32; off > 0; off >>= 1) vs += __shfl_xor(vs, off, 64);
    float r = rsqrtf(vs * (1.0f / 256.0f) + EPS_LN);
    int c = lane * 4;
    float o0 = fmaf(d0 * r, lg[c + 0], lb[c + 0]);
    float o1 = fmaf(d1 * r, lg[c + 1], lb[c + 1]);
    float o2 = fmaf(d2 * r, lg[c + 2], lb[c + 2]);
    float o3 = fmaf(d3 * r, lg[c + 3], lb[c + 3]);
    *(float4*)(out + base) = make_float4(o0, o1, o2, o3);
    float part = o0 * sw[c + 0] + o1 * sw[c + 1] + o2 * sw[c + 2] + o3 * sw[c + 3];
#pragma unroll
    for (int off = 32; off > 0; off >>= 1) part += __shfl_xor(part, off, 64);
    if (lane == 0)
        out[(size_t)N_NODES * 256 + node] = part + sb[0];
}

extern "C" void kernel_launch(void* const* d_in, const int* in_sizes, int n_in,
                              void* d_out, int out_size, void* d_ws, size_t ws_size,
                              hipStream_t stream) {
    if (ws_size < (size_t)100663296) return;  // 96 MiB budget (6 * 16 MiB)

    const float* x     = (const float*)d_in[0];
    const int*   esrc  = (const int*)d_in[1];
    const int*   edst  = (const int*)d_in[2];
    const float* eattr = (const float*)d_in[3];

    // ws layout: convb(16M) | qkvb(48M, [node][768]) | tb(16M) | vtb(16M) = 96 MiB
    bf16* convb = (bf16*)d_ws;
    bf16* qkvb  = convb + NH;
    bf16* tb    = qkvb + 3 * NH;
    bf16* vtb   = tb + NH;
    // overlays (raw byte-range reuse; all dead at time of overwrite):
    bf16* xb  = qkvb;       // x-cast, dead after layer-0 conv GEMM
    bf16* hb  = qkvb + NH;  // h, dead after next layer's conv GEMM
    bf16* pjb = qkvb;       // proj out, written after fattn consumed qkv

    char* scr = (char*)d_out;
    const size_t LBYTES = 393216 + 131072 + 131072 + 2048;
    int*   counts  = (int*)(scr + 2 * LBYTES);
    int*   offsets = counts + 32768;
    int*   cursor  = offsets + 32769;
    int*   srcp    = cursor + 32768;
    float* attrp   = (float*)(srcp + E_EDGES);

    (void)hipMemsetAsync(counts, 0, 32768 * sizeof(int), stream);
    k_hist<<<E_EDGES / 256, 256, 0, stream>>>(edst, counts);
    k_scan<<<1, 256, 0, stream>>>(counts, offsets, cursor);
    k_fill<<<E_EDGES / 256, 256, 0, stream>>>(esrc, edst, eattr, cursor, srcp, attrp);

    for (int L = 0; L < 2; ++L) {
        int bi = 5 + L * 11;
        char* base = scr + (size_t)L * LBYTES;
        bf16*  iwb = (bf16*)base;
        bf16*  owb = iwb + 196608;
        bf16*  cwT = owb + 65536;
        float* bns = (float*)(cwT + 65536);
        float* bnt = bns + 256;
        k_stage<<<513, 256, 0, stream>>>((const float*)d_in[bi + 0], (const float*)d_in[bi + 1],
                                         (const float*)d_in[bi + 2], (const float*)d_in[bi + 3],
                                         (const float*)d_in[bi + 4], (const float*)d_in[bi + 5],
                                         (const float*)d_in[bi + 7], iwb, owb, cwT, bns, bnt);
    }

    k_cvtb4<<<8192, 256, 0, stream>>>(xb, x);

    for (int L = 0; L < 2; ++L) {
        int bi = 5 + L * 11;
        char* base = scr + (size_t)L * LBYTES;
        bf16*  iwb = (bf16*)base;
        bf16*  owb = iwb + 196608;
        bf16*  cwT = owb + 65536;
        float* bns = (float*)(cwT + 65536);
        float* bnt = bns + 256;
        const float* ib = (const float*)d_in[bi + 6];
        const float* ob = (const float*)d_in[bi + 8];

        k_gemm<<<dim3(256, 2), 256, 0, stream>>>(L == 0 ? xb : hb, cwT, nullptr, tb, nullptr,
                                                 256, 0);
        k_gather<<<8192, 256, 0, stream>>>(tb, offsets, srcp, attrp, bns, bnt, convb);
        // fused QKV projection: Q pre-scaled, K to qkvb, V written transposed to vtb
        k_gemm<<<dim3(256, 6), 256, 0, stream>>>(convb, iwb, ib, qkvb, vtb, 768, 1);
        k_fattn<<<2048, 256, 0, stream>>>(qkvb, vtb, tb);
        k_gemm<<<dim3(256, 2), 256, 0, stream>>>(tb, owb, ob, pjb, nullptr, 256, 0);
        if (L == 0) {
            k_ln<<<8192, 256, 0, stream>>>(convb, pjb, (const float*)d_in[bi + 9],
                                           (const float*)d_in[bi + 10], hb);
        } else {
            k_lnout<<<8192, 256, 0, stream>>>(convb, pjb, (const float*)d_in[bi + 9],
                                              (const float*)d_in[bi + 10],
                                              (const float*)d_in[27], (const float*)d_in[28],
                                              (float*)d_out);
        }
    }
}

// Round 8
// 495.328 us; speedup vs baseline: 1.3404x; 1.0246x over previous
//
#include <hip/hip_runtime.h>
#include <hip/hip_bf16.h>
#include <math.h>

#define N_NODES 32768
#define E_EDGES 524288
#define NHID    256
#define HEAD_DIM 64
#define SEQ     512
#define EPS_LN  1e-5f
// 1/sqrt(64) * log2(e): folded into Q at the QKV-GEMM epilogue, so fattn scores
// are already in exp2 domain: p = exp2(s)
#define SM_SCALE 0.18033688011112042f

typedef __hip_bfloat16 bf16;
typedef __attribute__((ext_vector_type(8))) short short8;   // 8 bf16 (4 VGPRs)
typedef __attribute__((ext_vector_type(4))) float floatx4;  // MFMA accumulator
static const size_t NH = (size_t)N_NODES * NHID;  // 8,388,608

__device__ __forceinline__ void unpack2(unsigned int u, float& lo, float& hi) {
    union { float f; unsigned int i; } a, b;
    a.i = u << 16; b.i = u & 0xffff0000u;
    lo = a.f; hi = b.f;
}

// XOR-swizzled address into a row-major [R][64] bf16 LDS tile (128 B rows).
// byte = row*128 + col*2, then ^= (row&7)<<4 (guide G4 / T2).
__device__ __forceinline__ void* swzp(void* base, int row, int col) {
    return (char*)base + (((row << 7) + (col << 1)) ^ ((row & 7) << 4));
}

// async global->LDS, 16B per lane. LDS dest is wave-uniform base + lane*16 (m104).
__device__ __forceinline__ void gload16(const bf16* g, void* lds) {
    __builtin_amdgcn_global_load_lds((const __attribute__((address_space(1))) void*)g,
                                     (__attribute__((address_space(3))) void*)lds, 16, 0, 0);
}

// ---------------- fused staging: both layers' weights + x cast (was 3 launches) --------
// blk 0..512: layer0 (0..191 iw, 192..255 ow, 256..511 cwT, 512 BN fold)
// blk 513..1025: layer1 same; blk 1026..9217: x fp32->bf16 cast.
__global__ __launch_bounds__(256) void k_stage2(
    const float* __restrict__ cw0, const float* __restrict__ g0, const float* __restrict__ b0,
    const float* __restrict__ m0, const float* __restrict__ v0, const float* __restrict__ iw0,
    const float* __restrict__ ow0,
    const float* __restrict__ cw1, const float* __restrict__ g1, const float* __restrict__ b1,
    const float* __restrict__ m1, const float* __restrict__ v1, const float* __restrict__ iw1,
    const float* __restrict__ ow1,
    bf16* __restrict__ iwb0, bf16* __restrict__ owb0, bf16* __restrict__ cwT0,
    float* __restrict__ bns0, float* __restrict__ bnt0,
    bf16* __restrict__ iwb1, bf16* __restrict__ owb1, bf16* __restrict__ cwT1,
    float* __restrict__ bns1, float* __restrict__ bnt1,
    const float* __restrict__ x, bf16* __restrict__ xb) {
    const int blk = blockIdx.x;
    const int tid = threadIdx.x;
    if (blk >= 1026) {
        size_t i = (size_t)((blk - 1026) * 256 + tid) * 4;
        const float4 v = *(const float4*)(x + i);
        __align__(8) bf16 t4[4];
        t4[0] = __float2bfloat16(v.x);
        t4[1] = __float2bfloat16(v.y);
        t4[2] = __float2bfloat16(v.z);
        t4[3] = __float2bfloat16(v.w);
        *(uint2*)(xb + i) = *(uint2*)t4;
        return;
    }
    const int L = (blk >= 513);
    const int b2 = L ? blk - 513 : blk;
    const float* cw = L ? cw1 : cw0;
    const float* bng = L ? g1 : g0;
    const float* bnb = L ? b1 : b0;
    const float* bnm = L ? m1 : m0;
    const float* bnv = L ? v1 : v0;
    const float* iw = L ? iw1 : iw0;
    const float* ow = L ? ow1 : ow0;
    bf16* iwb = L ? iwb1 : iwb0;
    bf16* owb = L ? owb1 : owb0;
    bf16* cwT = L ? cwT1 : cwT0;
    float* bns = L ? bns1 : bns0;
    float* bnt = L ? bnt1 : bnt0;
    if (b2 < 256) {
        const float* src = (b2 < 192) ? iw : ow;
        bf16* dst = (b2 < 192) ? iwb : owb;
        size_t i = (size_t)((b2 < 192 ? b2 : b2 - 192) * 256 + tid) * 4;
        const float4 v = *(const float4*)(src + i);
        __align__(8) bf16 t4[4];
        t4[0] = __float2bfloat16(v.x);
        t4[1] = __float2bfloat16(v.y);
        t4[2] = __float2bfloat16(v.z);
        t4[3] = __float2bfloat16(v.w);
        *(uint2*)(dst + i) = *(uint2*)t4;
    } else if (b2 < 512) {
        const int k = b2 - 256;
        cwT[(size_t)tid * 256 + k] = __float2bfloat16(cw[(size_t)k * 256 + tid]);
    } else {
        float sv = bng[tid] * rsqrtf(bnv[tid] + EPS_LN);
        bns[tid] = sv;
        bnt[tid] = bnb[tid] - bnm[tid] * sv;
    }
}

// ---------------- CSR build: histogram -> scan -> fill ----------------
__global__ void k_hist(const int* __restrict__ edst, int* __restrict__ counts) {
    int e = blockIdx.x * 256 + threadIdx.x;
    atomicAdd(&counts[edst[e]], 1);
}

__global__ __launch_bounds__(256) void k_scan(const int* __restrict__ counts,
                                              int* __restrict__ offsets,
                                              int* __restrict__ cursor) {
    __shared__ int sums[256];
    const int tid = threadIdx.x;
    const int base = tid * 128;
    int s = 0;
    for (int i = 0; i < 128; ++i) s += counts[base + i];
    sums[tid] = s;
    __syncthreads();
    for (int off = 1; off < 256; off <<= 1) {
        int v = (tid >= off) ? sums[tid - off] : 0;
        __syncthreads();
        sums[tid] += v;
        __syncthreads();
    }
    int run = (tid == 0) ? 0 : sums[tid - 1];
    for (int i = 0; i < 128; ++i) {
        int c = counts[base + i];
        offsets[base + i] = run;
        cursor[base + i] = run;
        run += c;
    }
    if (tid == 255) offsets[32768] = run;
}

__global__ void k_fill(const int* __restrict__ esrc, const int* __restrict__ edst,
                       const float* __restrict__ eattr, int* __restrict__ cursor,
                       int* __restrict__ srcp, float* __restrict__ attrp) {
    int e = blockIdx.x * 256 + threadIdx.x;
    int d = edst[e];
    int slot = atomicAdd(&cursor[d], 1);
    srcp[slot] = esrc[e];
    attrp[slot] = eattr[e];
}

// ---------------- conv gather + fused BN: one wave per dst node; bf16 out ----------------
// Two edges per iteration (half-waves), 16 B/lane loads; 1-deep software pipeline:
// pair j+2's row load is in flight while pair j's FMAs run (breaks the serial
// shfl->load->FMA chain; loads of OOB prefetch lanes hit row 0 harmlessly and are
// discarded at loop exit).
__global__ __launch_bounds__(256) void k_gather(const bf16* __restrict__ t,
                                                const int* __restrict__ offsets,
                                                const int* __restrict__ srcp,
                                                const float* __restrict__ attrp,
                                                const float* __restrict__ bns,
                                                const float* __restrict__ bnt,
                                                bf16* __restrict__ conv) {
    const int node = (blockIdx.x * 256 + threadIdx.x) >> 6;
    const int lane = threadIdx.x & 63;
    const int half = lane >> 5;
    const int l32 = lane & 31;
    const int start = offsets[node];
    const int end = offsets[node + 1];
    float a[8];
#pragma unroll
    for (int i = 0; i < 8; ++i) a[i] = 0.f;
    for (int c0 = start; c0 < end; c0 += 64) {
        const int n = min(64, end - c0);
        int sidx = 0;
        float sa = 0.f;
        if (lane < n) {
            sidx = srcp[c0 + lane];
            sa = attrp[c0 + lane];
        }
        int s = __shfl(sidx, half, 64);
        float aw = __shfl(sa, half, 64);
        uint4 u = *(const uint4*)(t + (size_t)s * 256 + l32 * 8);
        for (int j = 0; j < n; j += 2) {
            const int e2 = (j + 2 + half) & 63;          // prefetch pair j+2
            const int s2 = __shfl(sidx, e2, 64);
            const float aw2 = __shfl(sa, e2, 64);
            const uint4 u2 = *(const uint4*)(t + (size_t)s2 * 256 + l32 * 8);
            float v0, v1, v2, v3, v4, v5, v6, v7;
            unpack2(u.x, v0, v1);
            unpack2(u.y, v2, v3);
            unpack2(u.z, v4, v5);
            unpack2(u.w, v6, v7);
            a[0] = fmaf(aw, v0, a[0]);
            a[1] = fmaf(aw, v1, a[1]);
            a[2] = fmaf(aw, v2, a[2]);
            a[3] = fmaf(aw, v3, a[3]);
            a[4] = fmaf(aw, v4, a[4]);
            a[5] = fmaf(aw, v5, a[5]);
            a[6] = fmaf(aw, v6, a[6]);
            a[7] = fmaf(aw, v7, a[7]);
            u = u2;
            aw = aw2;
        }
    }
#pragma unroll
    for (int i = 0; i < 8; ++i) a[i] += __shfl_xor(a[i], 32, 64);
    if (half == 0) {
        const int c = l32 * 8;
        const float4 s0 = *(const float4*)(bns + c);
        const float4 s1 = *(const float4*)(bns + c + 4);
        const float4 t0 = *(const float4*)(bnt + c);
        const float4 t1 = *(const float4*)(bnt + c + 4);
        __align__(16) bf16 tmp[8];
        tmp[0] = __float2bfloat16(fmaf(a[0], s0.x, t0.x));
        tmp[1] = __float2bfloat16(fmaf(a[1], s0.y, t0.y));
        tmp[2] = __float2bfloat16(fmaf(a[2], s0.z, t0.z));
        tmp[3] = __float2bfloat16(fmaf(a[3], s0.w, t0.w));
        tmp[4] = __float2bfloat16(fmaf(a[4], s1.x, t1.x));
        tmp[5] = __float2bfloat16(fmaf(a[5], s1.y, t1.y));
        tmp[6] = __float2bfloat16(fmaf(a[6], s1.z, t1.z));
        tmp[7] = __float2bfloat16(fmaf(a[7], s1.w, t1.w));
        *(uint4*)(conv + (size_t)node * 256 + c) = *(uint4*)tmp;
    }
}

// ---------------- MFMA GEMM: C[32768 x N] = A[32768x256] @ B, B staged as WT[n][k] ----
// T3-minimum double-buffer: STAGE(next) issued BEFORE compute of current K-step.
// qkvmode: Q-slice (gc<256) scaled by SM_SCALE; V-slice (gc>=512) written transposed
// to VT[(b*4+head)*64+d][512].
__global__ __launch_bounds__(256) void k_gemm(const bf16* __restrict__ A,
                                              const bf16* __restrict__ WT,
                                              const float* __restrict__ bias,
                                              bf16* __restrict__ C, bf16* __restrict__ VT,
                                              int ldc, int qkvmode) {
    __shared__ __align__(16) short As[2][128 * 64];
    __shared__ __align__(16) short Bs[2][128 * 64];
    const int tid = threadIdx.x;
    const int bm = blockIdx.x * 128;
    const int bn = blockIdx.y * 128;
    const int wid = tid >> 6;
    const int lane = tid & 63;
    const int wr = (wid >> 1) * 64;
    const int wc = (wid & 1) * 64;
    const int quad = lane >> 4;
    const int l16 = lane & 15;

    floatx4 acc[4][4];
#pragma unroll
    for (int mi = 0; mi < 4; ++mi)
#pragma unroll
        for (int ni = 0; ni < 4; ++ni)
            acc[mi][ni] = (floatx4){0.f, 0.f, 0.f, 0.f};

    auto STAGE = [&](int ks, int bf) {
#pragma unroll
        for (int t = 0; t < 4; ++t) {
            const int p = ((t * 4 + wid) << 10) + (lane << 4);  // linear LDS byte
            const int row = p >> 7;
            const int cb = (p & 127) ^ ((row & 7) << 4);        // inverse-swz source col
            gload16(A + (size_t)(bm + row) * 256 + ks * 64 + (cb >> 1),
                    (char*)&As[bf][0] + ((t * 4 + wid) << 10));
            gload16(WT + (size_t)(bn + row) * 256 + ks * 64 + (cb >> 1),
                    (char*)&Bs[bf][0] + ((t * 4 + wid) << 10));
        }
    };

    STAGE(0, 0);
    __syncthreads();
    for (int t = 0; t < 4; ++t) {
        const int buf = t & 1;
        if (t < 3) STAGE(t + 1, buf ^ 1);  // in flight during this step's MFMA
#pragma unroll
        for (int kk = 0; kk < 2; ++kk) {
            const int kcol = kk * 32 + quad * 8;
            short8 af[4], bfr[4];
#pragma unroll
            for (int mi = 0; mi < 4; ++mi)
                af[mi] = *(const short8*)swzp(&As[buf][0], wr + mi * 16 + l16, kcol);
#pragma unroll
            for (int ni = 0; ni < 4; ++ni)
                bfr[ni] = *(const short8*)swzp(&Bs[buf][0], wc + ni * 16 + l16, kcol);
#pragma unroll
            for (int mi = 0; mi < 4; ++mi)
#pragma unroll
                for (int ni = 0; ni < 4; ++ni)
                    acc[mi][ni] = __builtin_amdgcn_mfma_f32_16x16x32_bf16(af[mi], bfr[ni],
                                                                          acc[mi][ni], 0, 0, 0);
        }
        __syncthreads();  // drains prefetch + guards buf reuse
    }
    const float cs = (qkvmode && bn < 256) ? SM_SCALE : 1.0f;
    const bool vpath = (qkvmode && bn >= 512);
#pragma unroll
    for (int ni = 0; ni < 4; ++ni) {
        const int gc = bn + wc + ni * 16 + l16;
        const float bv = bias ? bias[gc] : 0.f;
#pragma unroll
        for (int mi = 0; mi < 4; ++mi) {
            const int gr = bm + wr + mi * 16 + quad * 4;
            if (vpath) {
                const int head = (gc - 512) >> 6;
                const int d = (gc - 512) & 63;
                const int bg = gr >> 9;
                const int sl = gr & 511;
                __align__(8) bf16 t4[4];
#pragma unroll
                for (int r = 0; r < 4; ++r) t4[r] = __float2bfloat16(acc[mi][ni][r] + bv);
                *(uint2*)(VT + (((size_t)((bg * 4 + head) * 64 + d)) << 9) + sl) = *(uint2*)t4;
            } else {
#pragma unroll
                for (int r = 0; r < 4; ++r)
                    C[(size_t)(gr + r) * ldc + gc] = __float2bfloat16((acc[mi][ni][r] + bv) * cs);
            }
        }
    }
}

// ---------------- fused proj-GEMM + residual + LayerNorm (+ReLU | +out/scores) --------
// BM=64, BN=256: each block computes FULL rows -> LN in-block. 4 waves each own
// 64 rows x 64 cols. LDS: As 2x8KB + Bs 2x32KB = 80 KB (2 blocks/CU exactly).
// Two-round LDS reduction (exact two-pass LN like the reference). mode=1 (layer 1)
// writes fp32 out + fused scores: score = rstd*SUM(d*lg*sw) + SUM(lb*sw) + sb.
// Removes k_ln/k_lnout launches + the 16 MB pjb write/read per layer, and keeps
// proj in fp32 (one less bf16 rounding than before).
__global__ __launch_bounds__(256) void k_gemmln(const bf16* __restrict__ A,
                                                const bf16* __restrict__ WT,
                                                const float* __restrict__ bias,
                                                const bf16* __restrict__ conv,
                                                const float* __restrict__ lg,
                                                const float* __restrict__ lb,
                                                bf16* __restrict__ h,
                                                const float* __restrict__ sw,
                                                const float* __restrict__ sb,
                                                float* __restrict__ out, int mode) {
    __shared__ __align__(16) short As[2][64 * 64];    // 2 x 8 KB
    __shared__ __align__(16) short Bs[2][256 * 64];   // 2 x 32 KB
    const int tid = threadIdx.x;
    const int bm = blockIdx.x * 64;
    const int wid = tid >> 6;
    const int lane = tid & 63;
    const int wc = wid * 64;
    const int quad = lane >> 4;
    const int l16 = lane & 15;

    floatx4 acc[4][4];
#pragma unroll
    for (int mi = 0; mi < 4; ++mi)
#pragma unroll
        for (int ni = 0; ni < 4; ++ni)
            acc[mi][ni] = (floatx4){0.f, 0.f, 0.f, 0.f};

    auto STAGE = [&](int ks, int bf) {
#pragma unroll
        for (int t = 0; t < 2; ++t) {  // A: 64 rows = 8 KB
            const int base = (t * 4 + wid) << 10;
            const int p = base + (lane << 4);
            const int row = p >> 7;
            const int cb = (p & 127) ^ ((row & 7) << 4);
            gload16(A + (size_t)(bm + row) * 256 + ks * 64 + (cb >> 1),
                    (char*)&As[bf][0] + base);
        }
#pragma unroll
        for (int t = 0; t < 8; ++t) {  // B: 256 rows = 32 KB
            const int base = (t * 4 + wid) << 10;
            const int p = base + (lane << 4);
            const int row = p >> 7;
            const int cb = (p & 127) ^ ((row & 7) << 4);
            gload16(WT + (size_t)row * 256 + ks * 64 + (cb >> 1), (char*)&Bs[bf][0] + base);
        }
    };

    STAGE(0, 0);
    __syncthreads();
    for (int t = 0; t < 4; ++t) {
        const int buf = t & 1;
        if (t < 3) STAGE(t + 1, buf ^ 1);
#pragma unroll
        for (int kk = 0; kk < 2; ++kk) {
            const int kcol = kk * 32 + quad * 8;
            short8 af[4], bfr[4];
#pragma unroll
            for (int mi = 0; mi < 4; ++mi)
                af[mi] = *(const short8*)swzp(&As[buf][0], mi * 16 + l16, kcol);
#pragma unroll
            for (int ni = 0; ni < 4; ++ni)
                bfr[ni] = *(const short8*)swzp(&Bs[buf][0], wc + ni * 16 + l16, kcol);
#pragma unroll
            for (int mi = 0; mi < 4; ++mi)
#pragma unroll
                for (int ni = 0; ni < 4; ++ni)
                    acc[mi][ni] = __builtin_amdgcn_mfma_f32_16x16x32_bf16(af[mi], bfr[ni],
                                                                          acc[mi][ni], 0, 0, 0);
        }
        __syncthreads();
    }

    // ---- epilogue: y = acc + bias + conv; two-pass LN across the 4 waves ----
#pragma unroll
    for (int ni = 0; ni < 4; ++ni) {
        const int gc = wc + ni * 16 + l16;
        const float bv = bias[gc];
#pragma unroll
        for (int mi = 0; mi < 4; ++mi) {
            const int gr = bm + mi * 16 + quad * 4;
#pragma unroll
            for (int r = 0; r < 4; ++r)
                acc[mi][ni][r] += bv + __bfloat162float(conv[(size_t)(gr + r) * 256 + gc]);
        }
    }

    float* red = (float*)&As[0][0];  // [64][4] row-sum partials (LDS reuse after k-loop)
    float* red2 = red + 256;         // [64][4] var partials
    float* red3 = red2 + 256;        // [64][4] score partials (mode)
    float* redb = red3 + 256;        // [4]     lb*sw partials (mode)

    // round 1: row sums
#pragma unroll
    for (int mi = 0; mi < 4; ++mi)
#pragma unroll
        for (int r = 0; r < 4; ++r) {
            float s1 = acc[mi][0][r] + acc[mi][1][r] + acc[mi][2][r] + acc[mi][3][r];
            s1 += __shfl_xor(s1, 1, 64);
            s1 += __shfl_xor(s1, 2, 64);
            s1 += __shfl_xor(s1, 4, 64);
            s1 += __shfl_xor(s1, 8, 64);
            if (l16 == 0) red[(mi * 16 + quad * 4 + r) * 4 + wid] = s1;
        }
    float lg4[4], lb4[4], w34[4];
#pragma unroll
    for (int ni = 0; ni < 4; ++ni) {
        const int gc = wc + ni * 16 + l16;
        lg4[ni] = lg[gc];
        lb4[ni] = lb[gc];
        w34[ni] = mode ? lg4[ni] * sw[gc] : 0.f;
    }
    if (mode) {
        float pb = 0.f;
#pragma unroll
        for (int ni = 0; ni < 4; ++ni) pb += lb4[ni] * sw[wc + ni * 16 + l16];
        pb += __shfl_xor(pb, 1, 64);
        pb += __shfl_xor(pb, 2, 64);
        pb += __shfl_xor(pb, 4, 64);
        pb += __shfl_xor(pb, 8, 64);
        if (lane == 0) redb[wid] = pb;
    }
    __syncthreads();

    // round 2: centered var (+ score partial)
    float mu_[4][4];
#pragma unroll
    for (int mi = 0; mi < 4; ++mi)
#pragma unroll
        for (int r = 0; r < 4; ++r) {
            const int row = mi * 16 + quad * 4 + r;
            const float mu = (red[row * 4 + 0] + red[row * 4 + 1] + red[row * 4 + 2] +
                              red[row * 4 + 3]) * (1.f / 256.f);
            mu_[mi][r] = mu;
            float s2 = 0.f, s3 = 0.f;
#pragma unroll
            for (int ni = 0; ni < 4; ++ni) {
                const float d = acc[mi][ni][r] - mu;
                s2 += d * d;
                s3 += d * w34[ni];
            }
            s2 += __shfl_xor(s2, 1, 64);
            s2 += __shfl_xor(s2, 2, 64);
            s2 += __shfl_xor(s2, 4, 64);
            s2 += __shfl_xor(s2, 8, 64);
            if (mode) {
                s3 += __shfl_xor(s3, 1, 64);
                s3 += __shfl_xor(s3, 2, 64);
                s3 += __shfl_xor(s3, 4, 64);
                s3 += __shfl_xor(s3, 8, 64);
            }
            if (l16 == 0) {
                red2[row * 4 + wid] = s2;
                if (mode) red3[row * 4 + wid] = s3;
            }
        }
    __syncthreads();

    const float B0 = mode ? (redb[0] + redb[1] + redb[2] + redb[3] + sb[0]) : 0.f;
#pragma unroll
    for (int mi = 0; mi < 4; ++mi)
#pragma unroll
        for (int r = 0; r < 4; ++r) {
            const int row = mi * 16 + quad * 4 + r;
            const int gr = bm + row;
            const float mu = mu_[mi][r];
            const float var = (red2[row * 4 + 0] + red2[row * 4 + 1] + red2[row * 4 + 2] +
                               red2[row * 4 + 3]) * (1.f / 256.f);
            const float rstd = rsqrtf(var + EPS_LN);
            if (!mode) {
#pragma unroll
                for (int ni = 0; ni < 4; ++ni) {
                    const int gc = wc + ni * 16 + l16;
                    const float o = fmaf((acc[mi][ni][r] - mu) * rstd, lg4[ni], lb4[ni]);
                    h[(size_t)gr * 256 + gc] = __float2bfloat16(fmaxf(o, 0.f));
                }
            } else {
#pragma unroll
                for (int ni = 0; ni < 4; ++ni) {
                    const int gc = wc + ni * 16 + l16;
                    out[(size_t)gr * 256 + gc] =
                        fmaf((acc[mi][ni][r] - mu) * rstd, lg4[ni], lb4[ni]);
                }
                if (wid == 0 && l16 == 0) {
                    const float S3 = red3[row * 4 + 0] + red3[row * 4 + 1] +
                                     red3[row * 4 + 2] + red3[row * 4 + 3];
                    out[(size_t)N_NODES * 256 + gr] = fmaf(rstd, S3, B0);
                }
            }
        }
}

// ---------------- MFMA flash attention (R4 structure — best measured: 46.8 us) ----------
// block = (graph, head, 64-row q-tile); 4 waves x 16 q-rows. XCD-chunked bid swizzle.
// LDS double-buffered K/V staged via global_load_lds; loads for tile kt+1 in flight
// during tile kt's compute (LDS staging amortizes L2 latency — R6's direct-stream
// variant was latency-bound at 125 us). No-max softmax (Q pre-scaled, exp2 domain,
// fmin clamp). l-sum via MFMA ones-column. NO setprio (R5: -5us/dispatch, m190).
__global__ __launch_bounds__(256) void k_fattn(const bf16* __restrict__ qkv,
                                               const bf16* __restrict__ vtb,
                                               bf16* __restrict__ ctx) {
    const int bid = ((blockIdx.x & 7) << 8) | (blockIdx.x >> 3);
    const int qt = bid & 7;
    const int head = (bid >> 3) & 3;
    const int b = bid >> 5;
    const int tid = threadIdx.x;
    const int wave = tid >> 6;
    const int lane = tid & 63;
    const int quad = lane >> 4;
    const int l16 = lane & 15;
    const int qrow0 = b * SEQ + qt * 64 + wave * 16;

    __shared__ __align__(16) short Ks[2][64 * 64];   // [key][d] swizzled, dbuf
    __shared__ __align__(16) short Vt[2][64 * 64];   // [d][key] swizzled, dbuf
    __shared__ __align__(16) short Ps[4][16 * 64];   // per-wave [q][key] swizzled

    const bf16* kbase = qkv + (size_t)(b * SEQ) * 768 + 256 + head * HEAD_DIM;
    const bf16* vbase = vtb + (size_t)((b * 4 + head) * 64) * 512;
    const int pbase = (wave << 10) + (lane << 4);

    short8 af_q[2];
    {
        const bf16* qp = qkv + (size_t)(qrow0 + l16) * 768 + head * HEAD_DIM + quad * 8;
        af_q[0] = *(const short8*)(qp);
        af_q[1] = *(const short8*)(qp + 32);
    }
    short8 ones;
#pragma unroll
    for (int j = 0; j < 8; ++j) ones[j] = (short)0x3F80;  // bf16(1.0)

    floatx4 acc[5];  // [0..3]: PV d-blocks; [4]: row-sum l
#pragma unroll
    for (int nt = 0; nt < 5; ++nt) acc[nt] = (floatx4){0.f, 0.f, 0.f, 0.f};

    auto STAGE = [&](int kt2, int bf) {
#pragma unroll
        for (int i = 0; i < 2; ++i) {
            const int p = (i << 12) + pbase;          // linear LDS byte
            const int row = p >> 7;                   // 0..63
            const int cb = (p & 127) ^ ((row & 7) << 4);  // inverse-swz source col
            gload16(kbase + (size_t)(kt2 * 64 + row) * 768 + (cb >> 1),
                    (char*)Ks[bf] + (i << 12) + (wave << 10));
            gload16(vbase + (size_t)row * 512 + kt2 * 64 + (cb >> 1),
                    (char*)Vt[bf] + (i << 12) + (wave << 10));
        }
    };

    STAGE(0, 0);
    __syncthreads();  // drain tile-0 loads

    for (int kt = 0; kt < 8; ++kt) {
        const int buf = kt & 1;
        if (kt < 7) STAGE(kt + 1, buf ^ 1);  // in flight during this tile's compute

        floatx4 sf[4];
#pragma unroll
        for (int f = 0; f < 4; ++f) {
            const short8 bk0 = *(const short8*)swzp(Ks[buf], f * 16 + l16, quad * 8);
            const short8 bk1 = *(const short8*)swzp(Ks[buf], f * 16 + l16, 32 + quad * 8);
            sf[f] = __builtin_amdgcn_mfma_f32_16x16x32_bf16(af_q[0], bk0,
                                                            (floatx4){0.f, 0.f, 0.f, 0.f}, 0, 0, 0);
            sf[f] = __builtin_amdgcn_mfma_f32_16x16x32_bf16(af_q[1], bk1, sf[f], 0, 0, 0);
        }

        bf16* psb = (bf16*)&Ps[wave][0];
#pragma unroll
        for (int r = 0; r < 4; ++r) {
            const float p0 = exp2f(fminf(sf[0][r], 80.f));
            const float p1 = exp2f(fminf(sf[1][r], 80.f));
            const float p2 = exp2f(fminf(sf[2][r], 80.f));
            const float p3 = exp2f(fminf(sf[3][r], 80.f));
            const int qr = quad * 4 + r;
            *(bf16*)swzp(psb, qr, l16)      = __float2bfloat16(p0);
            *(bf16*)swzp(psb, qr, 16 + l16) = __float2bfloat16(p1);
            *(bf16*)swzp(psb, qr, 32 + l16) = __float2bfloat16(p2);
            *(bf16*)swzp(psb, qr, 48 + l16) = __float2bfloat16(p3);
        }

#pragma unroll
        for (int c2 = 0; c2 < 2; ++c2) {
            const short8 ap = *(const short8*)swzp(psb, l16, c2 * 32 + quad * 8);
#pragma unroll
            for (int nt = 0; nt < 4; ++nt) {
                const short8 bv = *(const short8*)swzp(Vt[buf], nt * 16 + l16, c2 * 32 + quad * 8);
                acc[nt] = __builtin_amdgcn_mfma_f32_16x16x32_bf16(ap, bv, acc[nt], 0, 0, 0);
            }
            acc[4] = __builtin_amdgcn_mfma_f32_16x16x32_bf16(ap, ones, acc[4], 0, 0, 0);
        }
        __syncthreads();  // drains prefetch (tile ready) + guards buf reuse
    }

#pragma unroll
    for (int r = 0; r < 4; ++r) {
        const float inv = 1.f / acc[4][r];  // every column of acc[4] = row-sum l
        bf16* op = ctx + (size_t)(qrow0 + quad * 4 + r) * 256 + head * HEAD_DIM + l16;
        op[0]  = __float2bfloat16(acc[0][r] * inv);
        op[16] = __float2bfloat16(acc[1][r] * inv);
        op[32] = __float2bfloat16(acc[2][r] * inv);
        op[48] = __float2bfloat16(acc[3][r] * inv);
    }
}

extern "C" void kernel_launch(void* const* d_in, const int* in_sizes, int n_in,
                              void* d_out, int out_size, void* d_ws, size_t ws_size,
                              hipStream_t stream) {
    if (ws_size < (size_t)100663296) return;  // 96 MiB budget (6 * 16 MiB)

    const float* x     = (const float*)d_in[0];
    const int*   esrc  = (const int*)d_in[1];
    const int*   edst  = (const int*)d_in[2];
    const float* eattr = (const float*)d_in[3];

    // ws layout: convb(16M) | qkvb(48M, [node][768]) | tb(16M) | vtb(16M) = 96 MiB
    bf16* convb = (bf16*)d_ws;
    bf16* qkvb  = convb + NH;
    bf16* tb    = qkvb + 3 * NH;
    bf16* vtb   = tb + NH;
    // overlays (raw byte-range reuse; all dead at time of overwrite):
    bf16* xb  = qkvb;       // x-cast, dead after layer-0 conv GEMM
    bf16* hb  = qkvb + NH;  // h, dead after next layer's conv GEMM

    char* scr = (char*)d_out;
    const size_t LBYTES = 393216 + 131072 + 131072 + 2048;
    int*   counts  = (int*)(scr + 2 * LBYTES);
    int*   offsets = counts + 32768;
    int*   cursor  = offsets + 32769;
    int*   srcp    = cursor + 32768;
    float* attrp   = (float*)(srcp + E_EDGES);

    (void)hipMemsetAsync(counts, 0, 32768 * sizeof(int), stream);
    k_hist<<<E_EDGES / 256, 256, 0, stream>>>(edst, counts);
    k_scan<<<1, 256, 0, stream>>>(counts, offsets, cursor);
    k_fill<<<E_EDGES / 256, 256, 0, stream>>>(esrc, edst, eattr, cursor, srcp, attrp);

    // per-layer staged-weight pointers
    bf16*  iwb[2];
    bf16*  owb[2];
    bf16*  cwT[2];
    float* bns[2];
    float* bnt[2];
    for (int L = 0; L < 2; ++L) {
        char* base = scr + (size_t)L * LBYTES;
        iwb[L] = (bf16*)base;
        owb[L] = iwb[L] + 196608;
        cwT[L] = owb[L] + 65536;
        bns[L] = (float*)(cwT[L] + 65536);
        bnt[L] = bns[L] + 256;
    }
    k_stage2<<<9218, 256, 0, stream>>>(
        (const float*)d_in[5], (const float*)d_in[6], (const float*)d_in[7],
        (const float*)d_in[8], (const float*)d_in[9], (const float*)d_in[10],
        (const float*)d_in[12],
        (const float*)d_in[16], (const float*)d_in[17], (const float*)d_in[18],
        (const float*)d_in[19], (const float*)d_in[20], (const float*)d_in[21],
        (const float*)d_in[23],
        iwb[0], owb[0], cwT[0], bns[0], bnt[0],
        iwb[1], owb[1], cwT[1], bns[1], bnt[1],
        x, xb);

    for (int L = 0; L < 2; ++L) {
        int bi = 5 + L * 11;
        const float* ib = (const float*)d_in[bi + 6];
        const float* ob = (const float*)d_in[bi + 8];

        k_gemm<<<dim3(256, 2), 256, 0, stream>>>(L == 0 ? xb : hb, cwT[L], nullptr, tb,
                                                 nullptr, 256, 0);
        k_gather<<<8192, 256, 0, stream>>>(tb, offsets, srcp, attrp, bns[L], bnt[L], convb);
        // fused QKV projection: Q pre-scaled, K to qkvb, V written transposed to vtb
        k_gemm<<<dim3(256, 6), 256, 0, stream>>>(convb, iwb[L], ib, qkvb, vtb, 768, 1);
        k_fattn<<<2048, 256, 0, stream>>>(qkvb, vtb, tb);
        // fused proj-GEMM + residual + LN (+ReLU for L0 | +fp32 out + scores for L1)
        k_gemmln<<<512, 256, 0, stream>>>(tb, owb[L], ob, convb, (const float*)d_in[bi + 9],
                                          (const float*)d_in[bi + 10], hb,
                                          (const float*)d_in[27], (const float*)d_in[28],
                                          (float*)d_out, L);
    }
}